// Round 7
// baseline (132.393 us; speedup 1.0000x reference)
//
#include <hip/hip_runtime.h>
#include <hip/hip_fp16.h>
#include <math.h>

// sigAct: u0 = sigmoid(-(lam_b*conv(1-2x))/eps); 5 damped updates.
// conv = separable 17-tap Gaussian (sigma=2) in LDS, f32 accumulation.
// Round-7: 2-tile register-prefetch pipeline. Grid 768, each block does two
// adjacent 64x64 tiles; ALL global loads (both u-halos, both epilogue xl/c
// sets) issue at kernel entry -> tile-2 memory latency hides under tile-1
// compute. 6 launches, fp16 u ping-pong, xl=(x,lam) half2. Coop/grid.sync
// abandoned (round-6: L2 flush storm, 429MB fetch, 1181us; not capturable).

#define TILE 64
#define RAD  8
#define IN_W 80
#define HW   512
#define NIMG 24
#define NPIX ((size_t)HW * HW * NIMG)

// 1D normalized Gaussian, sigma=2, 17 taps: exp(-(k-8)^2/8) / 5.0131684
__device__ __constant__ const float GWc[17] = {
    6.6916e-05f, 4.3635e-04f, 2.2159612e-03f, 8.7643070e-03f,
    2.6995958e-02f, 6.4759932e-02f, 1.2098751e-01f, 1.7603572e-01f,
    1.9947466e-01f,
    1.7603572e-01f, 1.2098751e-01f, 6.4759932e-02f, 2.6995958e-02f,
    8.7643070e-03f, 2.2159612e-03f, 4.3635e-04f, 6.6916e-05f
};

struct alignas(8)  H4 { __half2 a, b; };
struct alignas(16) H8 { __half2 a, b, c, d; };

// sigmoid(-z) = 1/(1+exp(z)); inf->0, -inf->1.
__device__ __forceinline__ float inv1pexp(float z) {
    return __builtin_amdgcn_rcpf(1.0f + __expf(z));
}

// ---- write prefetched f32 tile to LDS as f = 1-2x (zero-pad OOB) ----
__device__ __forceinline__ void wstage_f32(const float4* qq, __half* sIn,
                                           int t, int row0, int col0) {
#pragma unroll
    for (int i = 0; i < 7; ++i) {
        int q = t + i * 256;
        if (q < 1600) {
            int r = q / 20, c4 = (q - r * 20) * 4;
            int gr = row0 + r - RAD, gc = col0 + c4 - RAD;
            H4 o;
            if (gr >= 0 && gr < HW && gc >= 0 && gc < HW) {
                float4 v = qq[i];
                o.a = __floats2half2_rn(1.f - 2.f * v.x, 1.f - 2.f * v.y);
                o.b = __floats2half2_rn(1.f - 2.f * v.z, 1.f - 2.f * v.w);
            } else { o.a = __floats2half2_rn(0.f, 0.f); o.b = o.a; }
            *reinterpret_cast<H4*>(&sIn[r * IN_W + c4]) = o;
        }
    }
}

// ---- write prefetched half tile to LDS as f = 1-2u (zero-pad OOB) ----
__device__ __forceinline__ void wstage_h(const H8* pp, __half* sIn,
                                         int t, int row0, int col0) {
#pragma unroll
    for (int i = 0; i < 4; ++i) {
        int q = t + i * 256;
        if (q < 800) {
            int r = q / 10, c8 = (q - r * 10) * 8;
            int gr = row0 + r - RAD, gc = col0 + c8 - RAD;
            H8 v;
            if (gr >= 0 && gr < HW && gc >= 0 && gc < HW) {
                const __half2 one2 = __floats2half2_rn(1.f, 1.f);
                v = pp[i];
                v.a = __hsub2(one2, __hadd2(v.a, v.a));
                v.b = __hsub2(one2, __hadd2(v.b, v.b));
                v.c = __hsub2(one2, __hadd2(v.c, v.c));
                v.d = __hsub2(one2, __hadd2(v.d, v.d));
            } else {
                v.a = __floats2half2_rn(0.f, 0.f);
                v.b = v.a; v.c = v.a; v.d = v.a;
            }
            *reinterpret_cast<H8*>(&sIn[r * IN_W + c8]) = v;
        }
    }
}

// ---- horizontal 17-tap pass: sIn[80][80] -> sTmp[80][64] ----
__device__ __forceinline__ void hpass(const __half* sIn, __half* sTmp, int t) {
#pragma unroll
    for (int i = 0; i < 5; ++i) {
        int gq = t + i * 256;              // 1280 groups: 80 rows x 16
        int r  = gq >> 4;
        int cp = (gq & 15) * 4;
        const __half* wp = &sIn[r * IN_W + cp];
        float w[20];
#pragma unroll
        for (int j = 0; j < 5; ++j) {      // 5 x ds_read_b64
            H4 h = *reinterpret_cast<const H4*>(wp + j * 4);
            float2 f0 = __half22float2(h.a);
            float2 f1 = __half22float2(h.b);
            w[j*4+0] = f0.x; w[j*4+1] = f0.y;
            w[j*4+2] = f1.x; w[j*4+3] = f1.y;
        }
        float a0 = 0.f, a1 = 0.f, a2 = 0.f, a3 = 0.f;
#pragma unroll
        for (int k = 0; k < 17; ++k) {
            float g = GWc[k];
            a0 += g * w[k];     a1 += g * w[k + 1];
            a2 += g * w[k + 2]; a3 += g * w[k + 3];
        }
        H4 o; o.a = __floats2half2_rn(a0, a1); o.b = __floats2half2_rn(a2, a3);
        *reinterpret_cast<H4*>(&sTmp[r * TILE + cp]) = o;
    }
}

// ---- vertical 17-tap + pointwise epilogue for one tile ----
template<int MODE> // 0=INIT 1=MID 2=FINAL
__device__ __forceinline__ void vp_ep(const __half* sTmp, const __half* sIn,
                                      const float* cp, const __half2* xp,
                                      size_t pbase, __half2* xl, void* uout,
                                      int cc, int rg) {
    float win[32];
#pragma unroll
    for (int j = 0; j < 32; ++j)
        win[j] = __half2float(sTmp[(rg * 16 + j) * TILE + cc]);
#pragma unroll
    for (int m = 0; m < 16; ++m) {
        float acc = 0.f;
#pragma unroll
        for (int k = 0; k < 17; ++k) acc += GWc[k] * win[m + k];
        size_t gidx = pbase + (size_t)m * HW;
        // sIn holds f=1-2u -> u = (1-f)/2 (for INIT, u==x)
        float uprev = 0.5f * (1.f -
            __half2float(sIn[(rg * 16 + m + RAD) * IN_W + (cc + RAD)]));
        if constexpr (MODE == 0) {
            float lam = 100.f * inv1pexp(-10.f * cp[m]);  // 100*sigmoid(10c)
            xl[gidx] = __floats2half2_rn(uprev, lam);     // (x, lam)
            ((__half*)uout)[gidx] = __float2half(inv1pexp(lam * acc * 0.1f));
        } else {
            float2 p = __half22float2(xp[m]);             // (x, lam)
            float tt = (uprev - p.x) * 10.f + p.y * acc;  // (u-x)/tau + lam*v
            float uu = inv1pexp(tt * 0.1f);               // sigmoid(-tt/eps)
            float res = 0.5f * uprev + 0.5f * uu;         // alpha = 0.5
            if constexpr (MODE == 2) ((float*)uout)[gidx] = res;
            else                     ((__half*)uout)[gidx] = __float2half(res);
        }
    }
}

template<int MODE> // 0=INIT 1=MID 2=FINAL
__global__ __launch_bounds__(256, 3) void sig_step2(
    const float* __restrict__ xg, const float* __restrict__ cgl,
    const __half* __restrict__ uin, __half2* __restrict__ xl,
    void* __restrict__ uout)
{
    __shared__ __half sIn [IN_W * IN_W];   // 12.8 KB
    __shared__ __half sTmp[IN_W * TILE];   // 10.2 KB

    const int t   = threadIdx.x;
    const int b   = blockIdx.x;            // 0..767
    const int img = b >> 5;                // 24 images
    const int rem = b & 31;                // 32 tile-pairs per image
    const int row0 = (rem >> 2) << 6;      // tile row 0..7
    const int c01  = (rem & 3) << 7;       // 0,128,256,384
    const int c02  = c01 + 64;
    const size_t ibase = (size_t)img * HW * HW;

    const int cc = t & 63, rg = t >> 6;
    const size_t pb1 = ibase + (size_t)(row0 + rg * 16) * HW + (c01 + cc);
    const size_t pb2 = pb1 + 64;

    // ===== issue ALL global loads up front (latency hides under compute) ====
    float4 q1[7], q2[7];
    H8     p1[4], p2[4];
    if constexpr (MODE == 0) {
        const float* xb = xg + ibase;
#pragma unroll
        for (int i = 0; i < 7; ++i) {
            int q = t + i * 256;
            int r = q / 20, c4 = (q - r * 20) * 4;
            int gr = row0 + r - RAD;
            int gc1 = c01 + c4 - RAD, gc2 = c02 + c4 - RAD;
            if (q < 1600 && gr >= 0 && gr < HW) {
                if (gc1 >= 0 && gc1 < HW)
                    q1[i] = *reinterpret_cast<const float4*>(&xb[(size_t)gr * HW + gc1]);
                if (gc2 >= 0 && gc2 < HW)
                    q2[i] = *reinterpret_cast<const float4*>(&xb[(size_t)gr * HW + gc2]);
            }
        }
    } else {
        const __half* ub = uin + ibase;
#pragma unroll
        for (int i = 0; i < 4; ++i) {
            int q = t + i * 256;
            int r = q / 10, c8 = (q - r * 10) * 8;
            int gr = row0 + r - RAD;
            int gc1 = c01 + c8 - RAD, gc2 = c02 + c8 - RAD;
            if (q < 800 && gr >= 0 && gr < HW) {
                if (gc1 >= 0 && gc1 < HW)
                    p1[i] = *reinterpret_cast<const H8*>(&ub[(size_t)gr * HW + gc1]);
                if (gc2 >= 0 && gc2 < HW)
                    p2[i] = *reinterpret_cast<const H8*>(&ub[(size_t)gr * HW + gc2]);
            }
        }
    }
    // epilogue data for both tiles (c for INIT, xl for MID/FINAL)
    float  cp1[16], cp2[16];
    __half2 xp1[16], xp2[16];
    if constexpr (MODE == 0) {
#pragma unroll
        for (int m = 0; m < 16; ++m) {
            cp1[m] = cgl[pb1 + (size_t)m * HW];
            cp2[m] = cgl[pb2 + (size_t)m * HW];
        }
    } else {
#pragma unroll
        for (int m = 0; m < 16; ++m) {   // xl may alias d_out: read before any store
            xp1[m] = xl[pb1 + (size_t)m * HW];
            xp2[m] = xl[pb2 + (size_t)m * HW];
        }
    }

    // ===== tile 1 =====
    if constexpr (MODE == 0) wstage_f32(q1, sIn, t, row0, c01);
    else                     wstage_h  (p1, sIn, t, row0, c01);
    __syncthreads();
    hpass(sIn, sTmp, t);
    __syncthreads();
    vp_ep<MODE>(sTmp, sIn, cp1, xp1, pb1, xl, uout, cc, rg);
    __syncthreads();

    // ===== tile 2 =====
    if constexpr (MODE == 0) wstage_f32(q2, sIn, t, row0, c02);
    else                     wstage_h  (p2, sIn, t, row0, c02);
    __syncthreads();
    hpass(sIn, sTmp, t);
    __syncthreads();
    vp_ep<MODE>(sTmp, sIn, cp2, xp2, pb2, xl, uout, cc, rg);
}

extern "C" void kernel_launch(void* const* d_in, const int* in_sizes, int n_in,
                              void* d_out, int out_size, void* d_ws, size_t ws_size,
                              hipStream_t stream) {
    const float* x = (const float*)d_in[0];
    const float* c = (const float*)d_in[1];

    __half* u0 = (__half*)d_ws;          // NPIX halfs = 12.6 MB
    __half* u1 = u0 + NPIX;              // 12.6 MB
    __half2* xl = (ws_size >= NPIX * 8)
        ? (__half2*)((char*)d_ws + NPIX * 4)
        : (__half2*)d_out;               // safe: epilogue preloads before store

    dim3 grid(768), block(256);
    sig_step2<0><<<grid, block, 0, stream>>>(x, c, nullptr, xl, u0);
    sig_step2<1><<<grid, block, 0, stream>>>(x, c, u0, xl, u1);
    sig_step2<1><<<grid, block, 0, stream>>>(x, c, u1, xl, u0);
    sig_step2<1><<<grid, block, 0, stream>>>(x, c, u0, xl, u1);
    sig_step2<1><<<grid, block, 0, stream>>>(x, c, u1, xl, u0);
    sig_step2<2><<<grid, block, 0, stream>>>(x, c, u0, xl, d_out);
}